// Round 1
// baseline (2204.069 us; speedup 1.0000x reference)
//
#include <hip/hip_runtime.h>
#include <cmath>

// Problem constants (match reference)
#define BB 512
#define TT 2048
#define IN 33
#define HH 64
#define OO 2

#define TPROJ 256   // t-steps per projection block
#define NB 2        // batches per recurrence wave (ILP)

// ---------------------------------------------------------------------------
// Kernel 1: input projection  xW[b,t,j] = sum_i x[b,t,i]*W_ih[j,i] + b_ih[j]
// One wave per (b, t-chunk). Lane j holds W_ih row j in registers; x row is
// wave-uniform (should scalarize to s_load). Output write is coalesced.
// ---------------------------------------------------------------------------
__global__ __launch_bounds__(64) void proj_kernel(
    const float* __restrict__ x, const float* __restrict__ W_ih,
    const float* __restrict__ b_ih, float* __restrict__ hid)
{
    const int j  = threadIdx.x;        // 0..63 output channel
    const int b  = blockIdx.x;         // batch
    const int t0 = blockIdx.y * TPROJ; // t chunk start

    float wih[IN];
#pragma unroll
    for (int i = 0; i < IN; ++i) wih[i] = W_ih[j * IN + i];
    const float bias = b_ih[j];

    for (int t = t0; t < t0 + TPROJ; ++t) {
        const float* xr = x + ((size_t)b * TT + t) * IN;  // wave-uniform addr
        float acc = bias;
#pragma unroll
        for (int i = 0; i < IN; ++i) acc = fmaf(wih[i], xr[i], acc);
        hid[((size_t)b * TT + t) * HH + j] = acc;
    }
}

// ---------------------------------------------------------------------------
// Kernel 2: recurrence. One wave per NB batches. Lane j keeps W_hh row j in
// registers (16 float4 = 64 VGPR). h ping-pongs through LDS (broadcast reads).
// Reads xW from hid[] and overwrites the same location with h (in-place).
// ---------------------------------------------------------------------------
__global__ __launch_bounds__(64) void rnn_kernel(
    const float* __restrict__ h0, const float* __restrict__ W_hh,
    const float* __restrict__ b_hh, float* __restrict__ hid)
{
    const int j  = threadIdx.x;
    const int b0 = blockIdx.x * NB;
    const int b1 = b0 + 1;

    __shared__ float buf[2][NB][HH];

    float4 w[16];
#pragma unroll
    for (int k = 0; k < 16; ++k)
        w[k] = ((const float4*)(W_hh + j * HH))[k];
    const float bias = b_hh[j];

    float ha = h0[b0 * HH + j];
    float hb = h0[b1 * HH + j];
    buf[0][0][j] = ha;
    buf[0][1][j] = hb;
    __syncthreads();

    float* hrow0 = hid + (size_t)b0 * TT * HH + j;
    float* hrow1 = hid + (size_t)b1 * TT * HH + j;

    int cur = 0;
    for (int t = 0; t < TT; ++t) {
        // xW for this step (independent of h; coalesced 256B per row)
        const float xa = hrow0[(size_t)t * HH];
        const float xb = hrow1[(size_t)t * HH];

        const float4* pa = (const float4*)buf[cur][0];
        const float4* pb = (const float4*)buf[cur][1];

        float a0 = 0.f, a1 = 0.f, a2 = 0.f, a3 = 0.f;
        float c0 = 0.f, c1 = 0.f, c2 = 0.f, c3 = 0.f;
#pragma unroll
        for (int k = 0; k < 16; ++k) {
            const float4 va = pa[k];
            const float4 vb = pb[k];
            a0 = fmaf(w[k].x, va.x, a0);
            a1 = fmaf(w[k].y, va.y, a1);
            a2 = fmaf(w[k].z, va.z, a2);
            a3 = fmaf(w[k].w, va.w, a3);
            c0 = fmaf(w[k].x, vb.x, c0);
            c1 = fmaf(w[k].y, vb.y, c1);
            c2 = fmaf(w[k].z, vb.z, c2);
            c3 = fmaf(w[k].w, vb.w, c3);
        }
        const float hna = tanhf(xa + bias + ((a0 + a1) + (a2 + a3)));
        const float hnb = tanhf(xb + bias + ((c0 + c1) + (c2 + c3)));

        hrow0[(size_t)t * HH] = hna;
        hrow1[(size_t)t * HH] = hnb;

        cur ^= 1;
        buf[cur][0][j] = hna;
        buf[cur][1][j] = hnb;
        __syncthreads();
    }
}

// ---------------------------------------------------------------------------
// Kernel 3: output projection  preds[b,t,o] = sum_j h[b,t,j]*W_ro[o,j] + b_ro[o]
// One thread per (b,t); W_ro is wave-uniform (scalarizable).
// ---------------------------------------------------------------------------
__global__ __launch_bounds__(256) void pred_kernel(
    const float* __restrict__ hid, const float* __restrict__ W_ro,
    const float* __restrict__ b_ro, float* __restrict__ preds)
{
    const size_t bt = (size_t)blockIdx.x * 256 + threadIdx.x; // 0..B*T-1
    const float4* hr = (const float4*)(hid + bt * HH);

    float p0 = 0.f, p1 = 0.f;
#pragma unroll
    for (int k = 0; k < 16; ++k) {
        const float4 h4 = hr[k];
        const float4 w0 = ((const float4*)W_ro)[k];
        const float4 w1 = ((const float4*)(W_ro + HH))[k];
        p0 = fmaf(w0.x, h4.x, fmaf(w0.y, h4.y, fmaf(w0.z, h4.z, fmaf(w0.w, h4.w, p0))));
        p1 = fmaf(w1.x, h4.x, fmaf(w1.y, h4.y, fmaf(w1.z, h4.z, fmaf(w1.w, h4.w, p1))));
    }
    float2 out;
    out.x = p0 + b_ro[0];
    out.y = p1 + b_ro[1];
    ((float2*)(preds))[bt] = out;
}

// ---------------------------------------------------------------------------
extern "C" void kernel_launch(void* const* d_in, const int* in_sizes, int n_in,
                              void* d_out, int out_size, void* d_ws, size_t ws_size,
                              hipStream_t stream)
{
    const float* x    = (const float*)d_in[0];
    const float* h0   = (const float*)d_in[1];
    const float* W_ih = (const float*)d_in[2];
    const float* W_hh = (const float*)d_in[3];
    const float* b_ih = (const float*)d_in[4];
    const float* b_hh = (const float*)d_in[5];
    const float* W_ro = (const float*)d_in[6];
    const float* b_ro = (const float*)d_in[7];

    float* out   = (float*)d_out;
    float* preds = out;                         // [B,T,O]
    float* hid   = out + (size_t)BB * TT * OO;  // [B,T,H] (also xW scratch)

    // 1) xW into hidden region (scratch until recurrence overwrites in place)
    proj_kernel<<<dim3(BB, TT / TPROJ), 64, 0, stream>>>(x, W_ih, b_ih, hid);

    // 2) recurrence, in place on hid
    rnn_kernel<<<BB / NB, 64, 0, stream>>>(h0, W_hh, b_hh, hid);

    // 3) predictions
    pred_kernel<<<(BB * TT) / 256, 256, 0, stream>>>(hid, W_ro, b_ro, preds);
}

// Round 2
// 1540.896 us; speedup vs baseline: 1.4304x; 1.4304x over previous
//
#include <hip/hip_runtime.h>
#include <cmath>

// Problem constants (match reference)
#define BB 512
#define TT 2048
#define IN 33
#define HH 64
#define OO 2

#define TPROJ 256   // t-steps per projection block

__device__ __forceinline__ float readlane_f(float v, int lane) {
    return __int_as_float(__builtin_amdgcn_readlane(__float_as_int(v), lane));
}

// tanh(x) = 1 - 2/(exp(2x)+1); exp(2x) = exp2(x * 2*log2(e)).
// v_exp_f32 + v_rcp_f32: ~1 ulp each; saturates to +/-1 correctly at +/-inf.
__device__ __forceinline__ float tanh_fast(float x) {
    float e = __builtin_amdgcn_exp2f(x * 2.8853900817779268f);
    float r = __builtin_amdgcn_rcpf(e + 1.0f);
    return fmaf(-2.0f, r, 1.0f);
}

// ---------------------------------------------------------------------------
// Kernel 1: input projection  xW[b,t,j] = sum_i x[b,t,i]*W_ih[j,i] + b_ih[j]
// One wave per (b, t-chunk). Lane j holds W_ih row j in registers; x row is
// wave-uniform (scalarizes to s_load). Output write is coalesced.
// ---------------------------------------------------------------------------
__global__ __launch_bounds__(64) void proj_kernel(
    const float* __restrict__ x, const float* __restrict__ W_ih,
    const float* __restrict__ b_ih, float* __restrict__ hid)
{
    const int j  = threadIdx.x;        // 0..63 output channel
    const int b  = blockIdx.x;         // batch
    const int t0 = blockIdx.y * TPROJ; // t chunk start

    float wih[IN];
#pragma unroll
    for (int i = 0; i < IN; ++i) wih[i] = W_ih[j * IN + i];
    const float bias = b_ih[j];

    for (int t = t0; t < t0 + TPROJ; ++t) {
        const float* xr = x + ((size_t)b * TT + t) * IN;  // wave-uniform addr
        float acc = bias;
#pragma unroll
        for (int i = 0; i < IN; ++i) acc = fmaf(wih[i], xr[i], acc);
        hid[((size_t)b * TT + t) * HH + j] = acc;
    }
}

// ---------------------------------------------------------------------------
// Kernel 2: recurrence. One wave per batch. Lane j keeps W_hh row j (64 VGPR)
// and h[j] in a register. h[k] broadcast via v_readlane (no LDS, no barrier).
// xW prefetched 4 steps ahead (double-buffered) to hide global latency.
// Reads xW from hid[] and overwrites the same location with h (in-place).
// ---------------------------------------------------------------------------
__global__ __launch_bounds__(64) void rnn_kernel(
    const float* __restrict__ h0, const float* __restrict__ W_hh,
    const float* __restrict__ b_hh, float* __restrict__ hid)
{
    const int j = threadIdx.x;
    const int b = blockIdx.x;

    float w[HH];
#pragma unroll
    for (int k = 0; k < HH; k += 4) {
        const float4 v = *(const float4*)(W_hh + j * HH + k);
        w[k] = v.x; w[k + 1] = v.y; w[k + 2] = v.z; w[k + 3] = v.w;
    }
    const float bias = b_hh[j];
    float h = h0[b * HH + j];

    float* hrow = hid + (size_t)b * TT * HH + j;

    // prefetch first group (t = 0..3)
    float pf[8];
#pragma unroll
    for (int i = 0; i < 4; ++i) pf[i] = hrow[(size_t)i * HH];

    for (int tg = 0; tg < TT; tg += 4) {
        const int buf  = (tg >> 2) & 1;
        const int nbuf = buf ^ 1;
        // prefetch next group (clamped; duplicate loads at the tail are unused)
        const int tn = (tg + 4 < TT) ? (tg + 4) : (TT - 4);
#pragma unroll
        for (int i = 0; i < 4; ++i)
            pf[nbuf * 4 + i] = hrow[(size_t)(tn + i) * HH];

#pragma unroll
        for (int i = 0; i < 4; ++i) {
            float a0 = 0.f, a1 = 0.f, a2 = 0.f, a3 = 0.f;
#pragma unroll
            for (int k = 0; k < HH; k += 4) {
                a0 = fmaf(w[k + 0], readlane_f(h, k + 0), a0);
                a1 = fmaf(w[k + 1], readlane_f(h, k + 1), a1);
                a2 = fmaf(w[k + 2], readlane_f(h, k + 2), a2);
                a3 = fmaf(w[k + 3], readlane_f(h, k + 3), a3);
            }
            const float z = pf[buf * 4 + i] + bias + ((a0 + a1) + (a2 + a3));
            h = tanh_fast(z);
            hrow[(size_t)(tg + i) * HH] = h;
        }
    }
}

// ---------------------------------------------------------------------------
// Kernel 3: output projection  preds[b,t,o] = sum_j h[b,t,j]*W_ro[o,j] + b_ro[o]
// One thread per (b,t); W_ro is wave-uniform (scalarizable).
// ---------------------------------------------------------------------------
__global__ __launch_bounds__(256) void pred_kernel(
    const float* __restrict__ hid, const float* __restrict__ W_ro,
    const float* __restrict__ b_ro, float* __restrict__ preds)
{
    const size_t bt = (size_t)blockIdx.x * 256 + threadIdx.x; // 0..B*T-1
    const float4* hr = (const float4*)(hid + bt * HH);

    float p0 = 0.f, p1 = 0.f;
#pragma unroll
    for (int k = 0; k < 16; ++k) {
        const float4 h4 = hr[k];
        const float4 w0 = ((const float4*)W_ro)[k];
        const float4 w1 = ((const float4*)(W_ro + HH))[k];
        p0 = fmaf(w0.x, h4.x, fmaf(w0.y, h4.y, fmaf(w0.z, h4.z, fmaf(w0.w, h4.w, p0))));
        p1 = fmaf(w1.x, h4.x, fmaf(w1.y, h4.y, fmaf(w1.z, h4.z, fmaf(w1.w, h4.w, p1))));
    }
    float2 out;
    out.x = p0 + b_ro[0];
    out.y = p1 + b_ro[1];
    ((float2*)(preds))[bt] = out;
}

// ---------------------------------------------------------------------------
extern "C" void kernel_launch(void* const* d_in, const int* in_sizes, int n_in,
                              void* d_out, int out_size, void* d_ws, size_t ws_size,
                              hipStream_t stream)
{
    const float* x    = (const float*)d_in[0];
    const float* h0   = (const float*)d_in[1];
    const float* W_ih = (const float*)d_in[2];
    const float* W_hh = (const float*)d_in[3];
    const float* b_ih = (const float*)d_in[4];
    const float* b_hh = (const float*)d_in[5];
    const float* W_ro = (const float*)d_in[6];
    const float* b_ro = (const float*)d_in[7];

    float* out   = (float*)d_out;
    float* preds = out;                         // [B,T,O]
    float* hid   = out + (size_t)BB * TT * OO;  // [B,T,H] (also xW scratch)

    // 1) xW into hidden region (scratch until recurrence overwrites in place)
    proj_kernel<<<dim3(BB, TT / TPROJ), 64, 0, stream>>>(x, W_ih, b_ih, hid);

    // 2) recurrence, in place on hid (one wave per batch)
    rnn_kernel<<<BB, 64, 0, stream>>>(h0, W_hh, b_hh, hid);

    // 3) predictions
    pred_kernel<<<(BB * TT) / 256, 256, 0, stream>>>(hid, W_ro, b_ro, preds);
}